// Round 6
// baseline (47.733 us; speedup 1.0000x reference)
//
#include <hip/hip_runtime.h>

#define HEADS 8
#define CH    64      // per-head dim == x channel dim
#define HW    4096
#define MTOK  256     // z tokens
#define DIMZ  256     // z feature dim
#define INNER 512     // heads*CH
#define LROWS 512     // HW/8 distinct query rows per head

typedef __attribute__((ext_vector_type(8))) __bf16 bf16x8;
typedef __attribute__((ext_vector_type(4))) float  f32x4;

// round-to-nearest-even f32 -> bf16 bits
__device__ __forceinline__ unsigned f2bf(float f) {
  unsigned u = __float_as_uint(f);
  return (u + 0x7fffu + ((u >> 16) & 1u)) >> 16;
}

__device__ __forceinline__ bf16x8 ld_bf8(const unsigned short* p) {
  uint4 v = *(const uint4*)p;
  return __builtin_bit_cast(bf16x8, v);
}

// ---------------------------------------------------------------------------
// Kernel 0 (prep): zbf = bf16(z) row-major (2048x256);
//   WkT/WvT = bf16(W^T) (512x256, k-contiguous); WoT = bf16(Wo^T) (64x512).
// ---------------------------------------------------------------------------
__global__ __launch_bounds__(256) void prep(
    const float* __restrict__ z, const float* __restrict__ Wk,
    const float* __restrict__ Wv, const float* __restrict__ Wo,
    unsigned short* __restrict__ zbf, unsigned short* __restrict__ WkT,
    unsigned short* __restrict__ WvT, unsigned short* __restrict__ WoT) {
  const int blk = blockIdx.x, tid = threadIdx.x;
  if (blk < 512) {                       // z: 2048*256 = 131072 float4
    int i = (blk * 256 + tid) * 4;
    float4 f = *(const float4*)(z + i);
    uint2 w;
    w.x = f2bf(f.x) | (f2bf(f.y) << 16);
    w.y = f2bf(f.z) | (f2bf(f.w) << 16);
    *(uint2*)(zbf + i) = w;
  } else if (blk < 768) {                // WkT / WvT: 512 n x 64 k-quads
    const bool isK = blk < 640;
    const float* __restrict__ W = isK ? Wk : Wv;
    unsigned short* __restrict__ WT = isK ? WkT : WvT;
    int gidx = (blk - (isK ? 512 : 640)) * 256 + tid;   // 0..32767
    int n = gidx >> 6, k0 = (gidx & 63) * 4;
    uint2 w;
    w.x = f2bf(W[(size_t)k0 * INNER + n])       | (f2bf(W[(size_t)(k0 + 1) * INNER + n]) << 16);
    w.y = f2bf(W[(size_t)(k0 + 2) * INNER + n]) | (f2bf(W[(size_t)(k0 + 3) * INNER + n]) << 16);
    *(uint2*)(WT + (size_t)n * DIMZ + k0) = w;
  } else {                               // WoT: 64 n x 128 k-quads
    int gidx = (blk - 768) * 256 + tid;  // 0..8191
    int n = gidx >> 7, k0 = (gidx & 127) * 4;
    uint2 w;
    w.x = f2bf(Wo[(size_t)k0 * CH + n])       | (f2bf(Wo[(size_t)(k0 + 1) * CH + n]) << 16);
    w.y = f2bf(Wo[(size_t)(k0 + 2) * CH + n]) | (f2bf(Wo[(size_t)(k0 + 3) * CH + n]) << 16);
    *(uint2*)(WoT + (size_t)n * INNER + k0) = w;
  }
}

// ---------------------------------------------------------------------------
// Kernel A (MFMA): klin = bf16(z@Wk + bk) row-major (2048x512);
//                  vt   = bf16(z@Wv + bv) in [b][h][c][key'], key' = cb*32+t.
// 512 blocks x 4 waves; 32x32 output tile per wave; fragments from global.
// ---------------------------------------------------------------------------
__global__ __launch_bounds__(256) void kv_mfma(
    const unsigned short* __restrict__ zbf,
    const unsigned short* __restrict__ WkT, const float* __restrict__ bk,
    const unsigned short* __restrict__ WvT, const float* __restrict__ bv,
    unsigned short* __restrict__ klin, unsigned short* __restrict__ vt) {
  const int t = threadIdx.x;
  const int lane = t & 63, wid = t >> 6;
  const int c = lane & 15, g = lane >> 4;
  const int mb = blockIdx.x;                 // 0..31
  const int bn = blockIdx.y;                 // 0..15
  const bool isK = bn < 8;
  const int nb = bn & 7;
  const unsigned short* __restrict__ WT = isK ? WkT : WvT;
  const float* __restrict__ bias = isK ? bk : bv;
  const int m0 = mb * 64 + (wid >> 1) * 32;
  const int n0 = nb * 64 + (wid & 1) * 32;

  f32x4 acc[2][2];
#pragma unroll
  for (int i = 0; i < 2; ++i)
#pragma unroll
    for (int j = 0; j < 2; ++j) acc[i][j] = (f32x4)0.f;

#pragma unroll
  for (int s = 0; s < 8; ++s) {
    const int k0 = s * 32;
    bf16x8 a0 = ld_bf8(zbf + (size_t)(m0 + c) * DIMZ + k0 + 8 * g);
    bf16x8 a1 = ld_bf8(zbf + (size_t)(m0 + 16 + c) * DIMZ + k0 + 8 * g);
    bf16x8 b0 = ld_bf8(WT + (size_t)(n0 + c) * DIMZ + k0 + 8 * g);
    bf16x8 b1 = ld_bf8(WT + (size_t)(n0 + 16 + c) * DIMZ + k0 + 8 * g);
    if (isK) {   // D[n][m]
      acc[0][0] = __builtin_amdgcn_mfma_f32_16x16x32_bf16(b0, a0, acc[0][0], 0, 0, 0);
      acc[0][1] = __builtin_amdgcn_mfma_f32_16x16x32_bf16(b1, a0, acc[0][1], 0, 0, 0);
      acc[1][0] = __builtin_amdgcn_mfma_f32_16x16x32_bf16(b0, a1, acc[1][0], 0, 0, 0);
      acc[1][1] = __builtin_amdgcn_mfma_f32_16x16x32_bf16(b1, a1, acc[1][1], 0, 0, 0);
    } else {     // D[m][n]
      acc[0][0] = __builtin_amdgcn_mfma_f32_16x16x32_bf16(a0, b0, acc[0][0], 0, 0, 0);
      acc[0][1] = __builtin_amdgcn_mfma_f32_16x16x32_bf16(a0, b1, acc[0][1], 0, 0, 0);
      acc[1][0] = __builtin_amdgcn_mfma_f32_16x16x32_bf16(a1, b0, acc[1][0], 0, 0, 0);
      acc[1][1] = __builtin_amdgcn_mfma_f32_16x16x32_bf16(a1, b1, acc[1][1], 0, 0, 0);
    }
  }

  if (isK) {
#pragma unroll
    for (int mt = 0; mt < 2; ++mt)
#pragma unroll
      for (int nt = 0; nt < 2; ++nt) {
        const int m = m0 + mt * 16 + c;
        const int n = n0 + nt * 16 + 4 * g;
        float4 b4 = *(const float4*)(bias + n);
        uint2 w;
        w.x = f2bf(acc[mt][nt][0] + b4.x) | (f2bf(acc[mt][nt][1] + b4.y) << 16);
        w.y = f2bf(acc[mt][nt][2] + b4.z) | (f2bf(acc[mt][nt][3] + b4.w) << 16);
        *(uint2*)(klin + (size_t)m * INNER + n) = w;
      }
  } else {
#pragma unroll
    for (int mt = 0; mt < 2; ++mt)
#pragma unroll
      for (int nt = 0; nt < 2; ++nt) {
        const int n = n0 + nt * 16 + c;
        const float bn1 = bias[n];
        const int m = m0 + mt * 16 + 4 * g;
        const int bb = m >> 8;
        const int mtk = m & 255;
        const int h = mtk >> 5, t0 = mtk & 31;
        const int cc = n & 63, cb = n >> 6;
        uint2 w;
        w.x = f2bf(acc[mt][nt][0] + bn1) | (f2bf(acc[mt][nt][1] + bn1) << 16);
        w.y = f2bf(acc[mt][nt][2] + bn1) | (f2bf(acc[mt][nt][3] + bn1) << 16);
        *(uint2*)(vt + ((size_t)((bb * HEADS + h) * CH + cc)) * MTOK + cb * 32 + t0) = w;
      }
  }
}

// ---------------------------------------------------------------------------
// Kernel B (MFMA attention): one wave per (b, h, 16-query tile).
// Grid 2048 -> 2 waves/SIMD (was 1): softmax of one wave overlaps MFMA of
// the other. Per-wave chain halved vs R5. log2e folded into Q scale; exp2f.
//  S'^T = K · Q^T (log2-domain) -> lane-local softmax -> P bf16 in LDS
//  O^T  = V^T · P -> deferred 1/rowsum -> bf16 stores to out2
// ---------------------------------------------------------------------------
__global__ __launch_bounds__(64) void attn_mfma(
    const float* __restrict__ x,
    const unsigned short* __restrict__ kbf,
    const unsigned short* __restrict__ vtbf,
    unsigned short* __restrict__ out2) {
  __shared__ unsigned short Psh[16 * 256];   // 8 KB
  char* Pb = (char*)Psh;
  const int t = threadIdx.x;
  const int c = t & 15, g = t >> 4;
  const int bid = blockIdx.x;                // b*256 + hh*32 + lt
  const int lt = bid & 31, hh = (bid >> 5) & 7, b = bid >> 8;
  const int qbase = lt * 16;
  const float* xs = x + (size_t)b * (HW * CH) + (size_t)hh * (LROWS * CH);
  const unsigned short* Kg = kbf + ((size_t)b * MTOK + hh * 32) * INNER; // [32 tok][512]
  const unsigned short* Vg = vtbf + (size_t)(b * HEADS + hh) * (CH * MTOK);

  // ---- Q fragment (B-operand); scale (1/8)*log2e folded in ----
  const float qs = 0.125f * 1.44269504089f;
  bf16x8 qfr[2];
#pragma unroll
  for (int ks = 0; ks < 2; ++ks) {
    const float* qp = xs + (size_t)(qbase + c) * CH + 32 * ks + 8 * g;
    float4 f0 = *(const float4*)qp;
    float4 f1 = *(const float4*)(qp + 4);
    uint4 u;
    u.x = f2bf(f0.x * qs) | (f2bf(f0.y * qs) << 16);
    u.y = f2bf(f0.z * qs) | (f2bf(f0.w * qs) << 16);
    u.z = f2bf(f1.x * qs) | (f2bf(f1.y * qs) << 16);
    u.w = f2bf(f1.z * qs) | (f2bf(f1.w * qs) << 16);
    qfr[ks] = __builtin_bit_cast(bf16x8, u);
  }

  // ---- S'^T = K · Q^T : acc[kf]; key' = 16*kf + (4g+r), col q = c ----
  f32x4 acc[16];
#pragma unroll
  for (int kf = 0; kf < 16; ++kf) acc[kf] = (f32x4)0.f;
#pragma unroll
  for (int kf = 0; kf < 16; ++kf) {
    const unsigned short* kp =
        Kg + (size_t)((kf & 1) * 16 + c) * INNER + (kf >> 1) * 64 + 8 * g;
    bf16x8 a0 = ld_bf8(kp);
    bf16x8 a1 = ld_bf8(kp + 32);
    acc[kf] = __builtin_amdgcn_mfma_f32_16x16x32_bf16(a0, qfr[0], acc[kf], 0, 0, 0);
    acc[kf] = __builtin_amdgcn_mfma_f32_16x16x32_bf16(a1, qfr[1], acc[kf], 0, 0, 0);
  }

  // ---- softmax in log2 domain (normalization deferred) + P write ----
  float m = acc[0][0];
#pragma unroll
  for (int kf = 0; kf < 16; ++kf)
    m = fmaxf(m, fmaxf(fmaxf(acc[kf][0], acc[kf][1]),
                       fmaxf(acc[kf][2], acc[kf][3])));
  m = fmaxf(m, __shfl_xor(m, 16));
  m = fmaxf(m, __shfl_xor(m, 32));
  float sum = 0.f;
  const int rowb = c * 512;                  // 256 ushort per P row
#pragma unroll
  for (int kf = 0; kf < 16; ++kf) {
    float e0 = exp2f(acc[kf][0] - m);
    float e1 = exp2f(acc[kf][1] - m);
    float e2 = exp2f(acc[kf][2] - m);
    float e3 = exp2f(acc[kf][3] - m);
    sum += (e0 + e1) + (e2 + e3);
    uint2 w;
    w.x = f2bf(e0) | (f2bf(e1) << 16);
    w.y = f2bf(e2) | (f2bf(e3) << 16);
    int off = (rowb + (16 * kf + 4 * g) * 2) ^ ((c & 7) << 4);
    *(uint2*)(Pb + off) = w;
  }
  sum += __shfl_xor(sum, 16);
  sum += __shfl_xor(sum, 32);
  const float inv = 1.f / sum;
  asm volatile("" ::: "memory");  // keep P writes before P reads

  // ---- O^T = V^T · P : o[cf], rows=channels, cols=queries ----
  f32x4 o[4];
#pragma unroll
  for (int cf = 0; cf < 4; ++cf) o[cf] = (f32x4)0.f;
#pragma unroll
  for (int ks = 0; ks < 8; ++ks) {
    bf16x8 p = __builtin_bit_cast(bf16x8,
        *(const uint4*)(Pb + ((c * 512 + (32 * ks + 8 * g) * 2) ^ ((c & 7) << 4))));
#pragma unroll
    for (int cf = 0; cf < 4; ++cf) {
      bf16x8 a = ld_bf8(Vg + (size_t)(16 * cf + c) * MTOK + 32 * ks + 8 * g);
      o[cf] = __builtin_amdgcn_mfma_f32_16x16x32_bf16(a, p, o[cf], 0, 0, 0);
    }
  }

  // ---- normalize + store bf16 ----
#pragma unroll
  for (int cf = 0; cf < 4; ++cf) {
    f32x4 r = o[cf] * inv;
    size_t row = (size_t)b * LROWS + qbase + c;
    uint2 w;
    w.x = f2bf(r[0]) | (f2bf(r[1]) << 16);
    w.y = f2bf(r[2]) | (f2bf(r[3]) << 16);
    *(uint2*)(out2 + row * INNER + hh * CH + 16 * cf + 4 * g) = w;
  }
}

// ---------------------------------------------------------------------------
// Kernel C (MFMA proj): O = out2 @ Wo + bo (4096x512x64), K split over 4
// waves (128 each), LDS reduce, then y[b, L*8+r] = x + O (broadcast 8x).
// ---------------------------------------------------------------------------
__global__ __launch_bounds__(256) void proj_mfma(
    const unsigned short* __restrict__ out2,
    const unsigned short* __restrict__ WoT, const float* __restrict__ bo,
    const float* __restrict__ x, float* __restrict__ y) {
  __shared__ __align__(16) float Sp[4][16][68];
  const int t = threadIdx.x, lane = t & 63, wid = t >> 6;
  const int c = lane & 15, g = lane >> 4;
  const int m0 = blockIdx.x * 16;            // 256 blocks over M=4096
  const int kw = wid * 128;

  f32x4 acc[4];
#pragma unroll
  for (int nt = 0; nt < 4; ++nt) acc[nt] = (f32x4)0.f;
#pragma unroll
  for (int s = 0; s < 4; ++s) {
    const int k0 = kw + s * 32;
    bf16x8 bfr = ld_bf8(out2 + (size_t)(m0 + c) * INNER + k0 + 8 * g);
#pragma unroll
    for (int nt = 0; nt < 4; ++nt) {
      bf16x8 afr = ld_bf8(WoT + (size_t)(nt * 16 + c) * INNER + k0 + 8 * g);
      acc[nt] = __builtin_amdgcn_mfma_f32_16x16x32_bf16(afr, bfr, acc[nt], 0, 0, 0);
    }
  }
#pragma unroll
  for (int nt = 0; nt < 4; ++nt)
    *(f32x4*)&Sp[wid][c][nt * 16 + 4 * g] = acc[nt];
  __syncthreads();

  const int i = t >> 4, j0 = (t & 15) * 4;
  float4 s0 = *(const float4*)&Sp[0][i][j0];
  float4 s1 = *(const float4*)&Sp[1][i][j0];
  float4 s2 = *(const float4*)&Sp[2][i][j0];
  float4 s3 = *(const float4*)&Sp[3][i][j0];
  float4 b4 = *(const float4*)(bo + j0);
  float4 o4 = make_float4(s0.x + s1.x + s2.x + s3.x + b4.x,
                          s0.y + s1.y + s2.y + s3.y + b4.y,
                          s0.z + s1.z + s2.z + s3.z + b4.z,
                          s0.w + s1.w + s2.w + s3.w + b4.w);
  const int m = m0 + i, bb = m >> 9, L = m & 511;
  const float* xr = x + (size_t)bb * (HW * CH) + (size_t)L * 8 * CH + j0;
  float*       yr = y + (size_t)bb * (HW * CH) + (size_t)L * 8 * CH + j0;
#pragma unroll
  for (int r = 0; r < 8; ++r) {
    float4 xv = *(const float4*)(xr + r * CH);
    float4 ov = make_float4(o4.x + xv.x, o4.y + xv.y, o4.z + xv.z, o4.w + xv.w);
    *(float4*)(yr + r * CH) = ov;
  }
}

extern "C" void kernel_launch(void* const* d_in, const int* in_sizes, int n_in,
                              void* d_out, int out_size, void* d_ws, size_t ws_size,
                              hipStream_t stream) {
  const float* x  = (const float*)d_in[0];
  const float* z  = (const float*)d_in[1];
  const float* Wk = (const float*)d_in[2];
  const float* bk = (const float*)d_in[3];
  const float* Wv = (const float*)d_in[4];
  const float* bv = (const float*)d_in[5];
  const float* Wo = (const float*)d_in[6];
  const float* bo = (const float*)d_in[7];
  float* y = (float*)d_out;

  // ws layout (ushort units): zbf 512K | WkT 128K | WvT 128K | WoT 32K |
  //                           klin 1M | vt 1M | out2 2M   (~10 MB total)
  unsigned short* zbf  = (unsigned short*)d_ws;
  unsigned short* WkT  = zbf  + (size_t)2048 * DIMZ;
  unsigned short* WvT  = WkT  + (size_t)INNER * DIMZ;
  unsigned short* WoT  = WvT  + (size_t)INNER * DIMZ;
  unsigned short* klin = WoT  + (size_t)CH * INNER;
  unsigned short* vt   = klin + (size_t)2048 * INNER;
  unsigned short* out2 = vt   + (size_t)2048 * INNER;

  prep<<<800, 256, 0, stream>>>(z, Wk, Wv, Wo, zbf, WkT, WvT, WoT);
  dim3 gA(32, 16);
  kv_mfma<<<gA, 256, 0, stream>>>(zbf, WkT, bk, WvT, bv, klin, vt);
  attn_mfma<<<2048, 64, 0, stream>>>(x, klin, vt, out2);
  proj_mfma<<<256, 256, 0, stream>>>(out2, WoT, bo, x, y);
}

// Round 7
// 45.953 us; speedup vs baseline: 1.0387x; 1.0387x over previous
//
#include <hip/hip_runtime.h>

#define HEADS 8
#define CH    64      // per-head dim == x channel dim
#define HW    4096
#define MTOK  256     // z tokens
#define DIMZ  256     // z feature dim
#define INNER 512     // heads*CH
#define LROWS 512     // HW/8 distinct query rows per head

typedef __attribute__((ext_vector_type(8))) __bf16 bf16x8;
typedef __attribute__((ext_vector_type(4))) float  f32x4;

// round-to-nearest-even f32 -> bf16 bits
__device__ __forceinline__ unsigned f2bf(float f) {
  unsigned u = __float_as_uint(f);
  return (u + 0x7fffu + ((u >> 16) & 1u)) >> 16;
}

__device__ __forceinline__ bf16x8 ld_bf8(const unsigned short* p) {
  uint4 v = *(const uint4*)p;
  return __builtin_bit_cast(bf16x8, v);
}

// 8 consecutive f32 -> bf16x8
__device__ __forceinline__ bf16x8 cvt8(const float* p) {
  float4 f0 = *(const float4*)p;
  float4 f1 = *(const float4*)(p + 4);
  uint4 u;
  u.x = f2bf(f0.x) | (f2bf(f0.y) << 16);
  u.y = f2bf(f0.z) | (f2bf(f0.w) << 16);
  u.z = f2bf(f1.x) | (f2bf(f1.y) << 16);
  u.w = f2bf(f1.z) | (f2bf(f1.w) << 16);
  return __builtin_bit_cast(bf16x8, u);
}

// ---------------------------------------------------------------------------
// Kernel 0 (prep_w): WkT/WvT = bf16(W^T) (512x256); WoT = bf16(Wo^T) (64x512).
// 288 blocks x 256 threads.
// ---------------------------------------------------------------------------
__global__ __launch_bounds__(256) void prep_w(
    const float* __restrict__ Wk, const float* __restrict__ Wv,
    const float* __restrict__ Wo,
    unsigned short* __restrict__ WkT, unsigned short* __restrict__ WvT,
    unsigned short* __restrict__ WoT) {
  const int blk = blockIdx.x, tid = threadIdx.x;
  if (blk < 256) {                       // WkT / WvT: 512 n x 64 k-quads
    const bool isK = blk < 128;
    const float* __restrict__ W = isK ? Wk : Wv;
    unsigned short* __restrict__ WT = isK ? WkT : WvT;
    int gidx = (blk & 127) * 256 + tid;  // 0..32767
    int n = gidx >> 6, k0 = (gidx & 63) * 4;
    uint2 w;
    w.x = f2bf(W[(size_t)k0 * INNER + n])       | (f2bf(W[(size_t)(k0 + 1) * INNER + n]) << 16);
    w.y = f2bf(W[(size_t)(k0 + 2) * INNER + n]) | (f2bf(W[(size_t)(k0 + 3) * INNER + n]) << 16);
    *(uint2*)(WT + (size_t)n * DIMZ + k0) = w;
  } else {                               // WoT: 64 n x 128 k-quads
    int gidx = (blk - 256) * 256 + tid;  // 0..8191
    int n = gidx >> 7, k0 = (gidx & 127) * 4;
    uint2 w;
    w.x = f2bf(Wo[(size_t)k0 * CH + n])       | (f2bf(Wo[(size_t)(k0 + 1) * CH + n]) << 16);
    w.y = f2bf(Wo[(size_t)(k0 + 2) * CH + n]) | (f2bf(Wo[(size_t)(k0 + 3) * CH + n]) << 16);
    *(uint2*)(WoT + (size_t)n * INNER + k0) = w;
  }
}

// ---------------------------------------------------------------------------
// Kernel B (fused kv-gen + attention): one block per (b, h, 128-query chunk).
// 512 threads = 8 waves. LDS: Ksh 32K [key'][ch] | VTsh 32K [ch][key'] |
// P 8K/wave. key' = cb*32 + t (validated permutation).
// Phase 1: waves 0-3 K = z@Wk+bk, waves 4-7 V = z@Wv+bv, MFMA from raw z
//          (inline bf16 cvt) + WT, writing swizzled LDS.
// Phase 2: per-wave 16-query attention (R6-validated math) from LDS.
// ---------------------------------------------------------------------------
__global__ __launch_bounds__(512) void fused_attn(
    const float* __restrict__ x, const float* __restrict__ z,
    const unsigned short* __restrict__ WkT, const float* __restrict__ bk,
    const unsigned short* __restrict__ WvT, const float* __restrict__ bv,
    unsigned short* __restrict__ out2) {
  __shared__ __align__(16) char lds[131072];
  const int t = threadIdx.x;
  const int lane = t & 63, wid = t >> 6;
  const int c = lane & 15, g = lane >> 4;
  const int bid = blockIdx.x;            // qc | hh | b
  const int qc = bid & 3, hh = (bid >> 2) & 7, b = bid >> 5;

  // ---------------- Phase 1: K/V generation into LDS ----------------
  {
    const bool isK = wid < 4;
    const unsigned short* __restrict__ WT = isK ? WkT : WvT;
    const float* __restrict__ bias = isK ? bk : bv;
    const float* zs = z + ((size_t)b * MTOK + hh * 32) * DIMZ;

    f32x4 acc[4][2][2];
#pragma unroll
    for (int tt = 0; tt < 4; ++tt)
#pragma unroll
      for (int i = 0; i < 2; ++i)
#pragma unroll
        for (int j = 0; j < 2; ++j) acc[tt][i][j] = (f32x4)0.f;

#pragma unroll
    for (int s = 0; s < 8; ++s) {
      const int k0 = s * 32;
      bf16x8 a0 = cvt8(zs + (size_t)c * DIMZ + k0 + 8 * g);
      bf16x8 a1 = cvt8(zs + (size_t)(16 + c) * DIMZ + k0 + 8 * g);
#pragma unroll
      for (int tt = 0; tt < 4; ++tt) {
        const int n0 = ((wid & 3) * 4 + tt) * 32;
        bf16x8 b0 = ld_bf8(WT + (size_t)(n0 + c) * DIMZ + k0 + 8 * g);
        bf16x8 b1 = ld_bf8(WT + (size_t)(n0 + 16 + c) * DIMZ + k0 + 8 * g);
        if (isK) {   // D[n][m]: rows = feature, col = token
          acc[tt][0][0] = __builtin_amdgcn_mfma_f32_16x16x32_bf16(b0, a0, acc[tt][0][0], 0, 0, 0);
          acc[tt][0][1] = __builtin_amdgcn_mfma_f32_16x16x32_bf16(b1, a0, acc[tt][0][1], 0, 0, 0);
          acc[tt][1][0] = __builtin_amdgcn_mfma_f32_16x16x32_bf16(b0, a1, acc[tt][1][0], 0, 0, 0);
          acc[tt][1][1] = __builtin_amdgcn_mfma_f32_16x16x32_bf16(b1, a1, acc[tt][1][1], 0, 0, 0);
        } else {     // D[m][n]: rows = token, col = feature
          acc[tt][0][0] = __builtin_amdgcn_mfma_f32_16x16x32_bf16(a0, b0, acc[tt][0][0], 0, 0, 0);
          acc[tt][0][1] = __builtin_amdgcn_mfma_f32_16x16x32_bf16(a0, b1, acc[tt][0][1], 0, 0, 0);
          acc[tt][1][0] = __builtin_amdgcn_mfma_f32_16x16x32_bf16(a1, b0, acc[tt][1][0], 0, 0, 0);
          acc[tt][1][1] = __builtin_amdgcn_mfma_f32_16x16x32_bf16(a1, b1, acc[tt][1][1], 0, 0, 0);
        }
      }
    }
    if (isK) {
      // element: feature n = n0+nt*16+4g+r, token = mt*16+c
#pragma unroll
      for (int tt = 0; tt < 4; ++tt) {
        const int n0 = ((wid & 3) * 4 + tt) * 32;
#pragma unroll
        for (int mt = 0; mt < 2; ++mt)
#pragma unroll
          for (int nt = 0; nt < 2; ++nt) {
            const int nb4 = n0 + nt * 16 + 4 * g;    // feature quad base
            float4 b4 = *(const float4*)(bias + nb4);
            const int key = (nb4 >> 6) * 32 + mt * 16 + c;
            const int ch0 = nb4 & 63;
            uint2 w;
            w.x = f2bf(acc[tt][mt][nt][0] + b4.x) | (f2bf(acc[tt][mt][nt][1] + b4.y) << 16);
            w.y = f2bf(acc[tt][mt][nt][2] + b4.z) | (f2bf(acc[tt][mt][nt][3] + b4.w) << 16);
            *(uint2*)(lds + ((key * 128 + ch0 * 2) ^ ((key & 7) << 4))) = w;
          }
      }
    } else {
      // element: token = mt*16+4g+r, feature n = n0+nt*16+c
#pragma unroll
      for (int tt = 0; tt < 4; ++tt) {
        const int n0 = ((wid & 3) * 4 + tt) * 32;
#pragma unroll
        for (int mt = 0; mt < 2; ++mt)
#pragma unroll
          for (int nt = 0; nt < 2; ++nt) {
            const int n = n0 + nt * 16 + c;
            const float bn1 = bias[n];
            const int ch = n & 63;
            const int key0 = (n >> 6) * 32 + mt * 16 + 4 * g;
            uint2 w;
            w.x = f2bf(acc[tt][mt][nt][0] + bn1) | (f2bf(acc[tt][mt][nt][1] + bn1) << 16);
            w.y = f2bf(acc[tt][mt][nt][2] + bn1) | (f2bf(acc[tt][mt][nt][3] + bn1) << 16);
            *(uint2*)(lds + 32768 + ((ch * 512 + key0 * 2) ^ ((ch & 7) << 4))) = w;
          }
      }
    }
  }
  __syncthreads();

  // ---------------- Phase 2: 16-query attention per wave ----------------
  const char* Kb = lds;
  const char* Vb = lds + 32768;
  char* Pb = lds + 65536 + wid * 8192;
  const int qbase = qc * 128 + wid * 16;
  const float* xs = x + (size_t)b * (HW * CH) + (size_t)hh * (LROWS * CH);

  // Q fragment (B-operand); scale (1/8)*log2e folded in
  const float qs = 0.125f * 1.44269504089f;
  bf16x8 qfr[2];
#pragma unroll
  for (int ks = 0; ks < 2; ++ks) {
    const float* qp = xs + (size_t)(qbase + c) * CH + 32 * ks + 8 * g;
    float4 f0 = *(const float4*)qp;
    float4 f1 = *(const float4*)(qp + 4);
    uint4 u;
    u.x = f2bf(f0.x * qs) | (f2bf(f0.y * qs) << 16);
    u.y = f2bf(f0.z * qs) | (f2bf(f0.w * qs) << 16);
    u.z = f2bf(f1.x * qs) | (f2bf(f1.y * qs) << 16);
    u.w = f2bf(f1.z * qs) | (f2bf(f1.w * qs) << 16);
    qfr[ks] = __builtin_bit_cast(bf16x8, u);
  }

  // S'^T = K . Q^T : acc[kf]; key' = 16*kf + (4g+r), col q = c
  f32x4 acc[16];
#pragma unroll
  for (int kf = 0; kf < 16; ++kf) acc[kf] = (f32x4)0.f;
#pragma unroll
  for (int kf = 0; kf < 16; ++kf) {
    const int key = 16 * kf + c;
    bf16x8 a0 = __builtin_bit_cast(bf16x8,
        *(const uint4*)(Kb + ((key * 128 + 16 * g) ^ ((key & 7) << 4))));
    bf16x8 a1 = __builtin_bit_cast(bf16x8,
        *(const uint4*)(Kb + ((key * 128 + 64 + 16 * g) ^ ((key & 7) << 4))));
    acc[kf] = __builtin_amdgcn_mfma_f32_16x16x32_bf16(a0, qfr[0], acc[kf], 0, 0, 0);
    acc[kf] = __builtin_amdgcn_mfma_f32_16x16x32_bf16(a1, qfr[1], acc[kf], 0, 0, 0);
  }

  // softmax in log2 domain (normalization deferred) + P write
  float m = acc[0][0];
#pragma unroll
  for (int kf = 0; kf < 16; ++kf)
    m = fmaxf(m, fmaxf(fmaxf(acc[kf][0], acc[kf][1]),
                       fmaxf(acc[kf][2], acc[kf][3])));
  m = fmaxf(m, __shfl_xor(m, 16));
  m = fmaxf(m, __shfl_xor(m, 32));
  float sum = 0.f;
  const int rowb = c * 512;               // 256 ushort per P row
#pragma unroll
  for (int kf = 0; kf < 16; ++kf) {
    float e0 = exp2f(acc[kf][0] - m);
    float e1 = exp2f(acc[kf][1] - m);
    float e2 = exp2f(acc[kf][2] - m);
    float e3 = exp2f(acc[kf][3] - m);
    sum += (e0 + e1) + (e2 + e3);
    uint2 w;
    w.x = f2bf(e0) | (f2bf(e1) << 16);
    w.y = f2bf(e2) | (f2bf(e3) << 16);
    *(uint2*)(Pb + ((rowb + (16 * kf + 4 * g) * 2) ^ ((c & 7) << 4))) = w;
  }
  sum += __shfl_xor(sum, 16);
  sum += __shfl_xor(sum, 32);
  const float inv = 1.f / sum;
  asm volatile("" ::: "memory");  // keep P writes before P reads

  // O^T = V^T . P : o[cf], rows=channels, cols=queries
  f32x4 o[4];
#pragma unroll
  for (int cf = 0; cf < 4; ++cf) o[cf] = (f32x4)0.f;
#pragma unroll
  for (int ks = 0; ks < 8; ++ks) {
    bf16x8 p = __builtin_bit_cast(bf16x8,
        *(const uint4*)(Pb + ((c * 512 + (32 * ks + 8 * g) * 2) ^ ((c & 7) << 4))));
#pragma unroll
    for (int cf = 0; cf < 4; ++cf) {
      const int ch = 16 * cf + c;
      bf16x8 a = __builtin_bit_cast(bf16x8,
          *(const uint4*)(Vb + ((ch * 512 + (32 * ks + 8 * g) * 2) ^ ((ch & 7) << 4))));
      o[cf] = __builtin_amdgcn_mfma_f32_16x16x32_bf16(a, p, o[cf], 0, 0, 0);
    }
  }

  // normalize + store bf16
#pragma unroll
  for (int cf = 0; cf < 4; ++cf) {
    f32x4 r = o[cf] * inv;
    size_t row = (size_t)b * LROWS + qbase + c;
    uint2 w;
    w.x = f2bf(r[0]) | (f2bf(r[1]) << 16);
    w.y = f2bf(r[2]) | (f2bf(r[3]) << 16);
    *(uint2*)(out2 + row * INNER + hh * CH + 16 * cf + 4 * g) = w;
  }
}

// ---------------------------------------------------------------------------
// Kernel C (MFMA proj): O = out2 @ Wo + bo (4096x512x64), K split over 4
// waves (128 each), LDS reduce, then y[b, L*8+r] = x + O (broadcast 8x).
// ---------------------------------------------------------------------------
__global__ __launch_bounds__(256) void proj_mfma(
    const unsigned short* __restrict__ out2,
    const unsigned short* __restrict__ WoT, const float* __restrict__ bo,
    const float* __restrict__ x, float* __restrict__ y) {
  __shared__ __align__(16) float Sp[4][16][68];
  const int t = threadIdx.x, lane = t & 63, wid = t >> 6;
  const int c = lane & 15, g = lane >> 4;
  const int m0 = blockIdx.x * 16;            // 256 blocks over M=4096
  const int kw = wid * 128;

  f32x4 acc[4];
#pragma unroll
  for (int nt = 0; nt < 4; ++nt) acc[nt] = (f32x4)0.f;
#pragma unroll
  for (int s = 0; s < 4; ++s) {
    const int k0 = kw + s * 32;
    bf16x8 bfr = ld_bf8(out2 + (size_t)(m0 + c) * INNER + k0 + 8 * g);
#pragma unroll
    for (int nt = 0; nt < 4; ++nt) {
      bf16x8 afr = ld_bf8(WoT + (size_t)(nt * 16 + c) * INNER + k0 + 8 * g);
      acc[nt] = __builtin_amdgcn_mfma_f32_16x16x32_bf16(afr, bfr, acc[nt], 0, 0, 0);
    }
  }
#pragma unroll
  for (int nt = 0; nt < 4; ++nt)
    *(f32x4*)&Sp[wid][c][nt * 16 + 4 * g] = acc[nt];
  __syncthreads();

  const int i = t >> 4, j0 = (t & 15) * 4;
  float4 s0 = *(const float4*)&Sp[0][i][j0];
  float4 s1 = *(const float4*)&Sp[1][i][j0];
  float4 s2 = *(const float4*)&Sp[2][i][j0];
  float4 s3 = *(const float4*)&Sp[3][i][j0];
  float4 b4 = *(const float4*)(bo + j0);
  float4 o4 = make_float4(s0.x + s1.x + s2.x + s3.x + b4.x,
                          s0.y + s1.y + s2.y + s3.y + b4.y,
                          s0.z + s1.z + s2.z + s3.z + b4.z,
                          s0.w + s1.w + s2.w + s3.w + b4.w);
  const int m = m0 + i, bb = m >> 9, L = m & 511;
  const float* xr = x + (size_t)bb * (HW * CH) + (size_t)L * 8 * CH + j0;
  float*       yr = y + (size_t)bb * (HW * CH) + (size_t)L * 8 * CH + j0;
#pragma unroll
  for (int r = 0; r < 8; ++r) {
    float4 xv = *(const float4*)(xr + r * CH);
    float4 ov = make_float4(o4.x + xv.x, o4.y + xv.y, o4.z + xv.z, o4.w + xv.w);
    *(float4*)(yr + r * CH) = ov;
  }
}

extern "C" void kernel_launch(void* const* d_in, const int* in_sizes, int n_in,
                              void* d_out, int out_size, void* d_ws, size_t ws_size,
                              hipStream_t stream) {
  const float* x  = (const float*)d_in[0];
  const float* z  = (const float*)d_in[1];
  const float* Wk = (const float*)d_in[2];
  const float* bk = (const float*)d_in[3];
  const float* Wv = (const float*)d_in[4];
  const float* bv = (const float*)d_in[5];
  const float* Wo = (const float*)d_in[6];
  const float* bo = (const float*)d_in[7];
  float* y = (float*)d_out;

  // ws layout (ushort units): WkT 128K | WvT 128K | WoT 32K | out2 1M  (~2.6 MB)
  unsigned short* WkT  = (unsigned short*)d_ws;
  unsigned short* WvT  = WkT + (size_t)INNER * DIMZ;
  unsigned short* WoT  = WvT + (size_t)INNER * DIMZ;
  unsigned short* out2 = WoT + (size_t)CH * INNER;

  prep_w<<<288, 256, 0, stream>>>(Wk, Wv, Wo, WkT, WvT, WoT);
  fused_attn<<<256, 512, 0, stream>>>(x, z, WkT, bk, WvT, bv, out2);
  proj_mfma<<<256, 256, 0, stream>>>(out2, WoT, bo, x, y);
}